// Round 6
// baseline (386.210 us; speedup 1.0000x reference)
//
#include <hip/hip_runtime.h>
#include <hip/hip_bf16.h>

typedef unsigned short ushort;
typedef unsigned int   uint;
typedef __bf16 bfrag_t __attribute__((ext_vector_type(8)));   // 8 bf16 = 4 VGPRs
typedef float  ffrag_t __attribute__((ext_vector_type(4)));   // 4 f32 acc

#define NB   8192   // batch
#define LL   224    // spectral bands
#define SS   25     // K*K
#define CTR  12     // center index
#define DD   128    // model dim
#define PP   6      // endmembers
#define HID  64     // hidden
#define NKC  7      // K-chunks of 32 (224/32)
#define NMT  2      // M-tiles of 16 (1 batch * 32 rows)  [R6: GPB=1, 256 thr]
#define NNT  24     // n-tiles of 16 (384 cols = wk|wv|wq)
#define VST  132    // ushort LDS row stride for keys/vals
#define VBASE (SS * VST)                       // 3300: vals base in alds
#define WPK_ELEMS (NKC * NNT * 64 * 8)         // 86016
#define FC1_ELEMS (4 * 16 * 64 * 8)            // 32768

__device__ __forceinline__ float f_sigmoid(float x) { return 1.0f / (1.0f + __expf(-x)); }
__device__ __forceinline__ ushort f2bf(float f) {
    __hip_bfloat16 h = __float2bfloat16(f);
    ushort u; __builtin_memcpy(&u, &h, 2); return u;
}
__device__ __forceinline__ float bfu2f(ushort u) {
    uint v = ((uint)u) << 16; float f; __builtin_memcpy(&f, &v, 4); return f;
}

// ---- k0: pack [wk|wv|wq] (24 tiles) + [f1f|f1g|s1f|s1g] (16 tiles); zero stats
// B-frag: lane holds B[k = kc*32+(lane>>4)*8+j][n = nt*16+(lane&15)]
__global__ __launch_bounds__(256) void k0_pack(
    const float* __restrict__ wk_w, const float* __restrict__ wv_w,
    const float* __restrict__ wq_w,
    const float* __restrict__ f1_fw, const float* __restrict__ f1_gw,
    const float* __restrict__ s1_fw, const float* __restrict__ s1_gw,
    ushort* __restrict__ wpack, ushort* __restrict__ fc1pack,
    float* __restrict__ stats)
{
    const int blk = blockIdx.x;
    if (blk == 0) stats[threadIdx.x] = 0.f;     // 256 entries, zero for kC atomics
    if (blk < NNT) {                            // wkvq: K=224, ld=128
        const int nt  = blk;
        const int mat = nt >> 3;
        const float* w = mat == 0 ? wk_w : (mat == 1 ? wv_w : wq_w);
        const int cb = (nt & 7) * 16;
        for (int e = threadIdx.x; e < NKC * 64 * 8; e += 256) {
            int j    = e & 7;
            int lane = (e >> 3) & 63;
            int kc   = e >> 9;
            int k = kc * 32 + ((lane >> 4) << 3) + j;
            int c = cb + (lane & 15);
            wpack[((kc * NNT + nt) * 64 + lane) * 8 + j] = f2bf(w[k * DD + c]);
        }
    } else {                                    // fc1: K=128, ld=64, 4 mats
        const int nt = blk - NNT;               // 0..15
        const int m2 = nt >> 2;                 // 0:f1f 1:f1g 2:s1f 3:s1g
        const float* w = m2 == 0 ? f1_fw : (m2 == 1 ? f1_gw : (m2 == 2 ? s1_fw : s1_gw));
        const int cb = (nt & 3) * 16;
        for (int e = threadIdx.x; e < 4 * 64 * 8; e += 256) {
            int j    = e & 7;
            int lane = (e >> 3) & 63;
            int kc   = e >> 9;
            int k = kc * 32 + ((lane >> 4) << 3) + j;
            int c = cb + (lane & 15);
            fc1pack[((kc * 16 + nt) * 64 + lane) * 8 + j] = f2bf(w[k * HID + c]);
        }
    }
}

// ---- kA: MFMA K/V/Q GEMM + attention + nearby gate + swish -----------------
// R6: 256 threads = 4 waves, ONE batch per block (8192 blocks).
// Wave w owns K-tiles {w, w+4}, V-tiles {8+w, 12+w}, Q-tiles {16+w, 20+w}
// -> col slices c0 = w*16+(lane&15) and c1 = c0+64.
__global__ __launch_bounds__(256, 4) void kA_front(
    const float* __restrict__ x,
    const ushort* __restrict__ wpack,
    const float* __restrict__ wk_b, const float* __restrict__ wv_b,
    const float* __restrict__ wq_b,
    const float* __restrict__ ng_w, const float* __restrict__ ng_b,
    ushort* __restrict__ swv_ws)
{
    // A fragments: 2 mt * 7 kc * 64 lanes * 8 = 7168 ushort (14336 B)
    // after GEMM reused: keys[0:3300) vals[3300:6600) as [s][VST] ushort
    __shared__ ushort alds[NMT * NKC * 64 * 8];
    __shared__ float  qv[DD];
    __shared__ float  att[4 * 26];
    __shared__ float  red[2];

    const int t    = threadIdx.x;
    const int wave = t >> 6;
    const int lane = t & 63;

    const int c0 = wave * 16 + (lane & 15);
    const int c1 = c0 + 64;
    const float biask0 = wk_b[c0], biask1 = wk_b[c1];
    const float biasv0 = wv_b[c0], biasv1 = wv_b[c1];
    const float biasq0 = wq_b[c0], biasq1 = wq_b[c1];
    const float ngw    = ng_w[t & 127];

    // ---- phase 1: batched x prefetch (1400 float4), then scatter ----------
    const float4* xb4 = (const float4*)(x + (size_t)blockIdx.x * (LL * SS));  // 5600 f32
    float4 xf[6];
#pragma unroll
    for (int k = 0; k < 6; ++k) {
        int q = t + k * 256;
        if (q < 1400) xf[k] = xb4[q];
    }
#pragma unroll
    for (int k = 0; k < 6; ++k) {
        int q = t + k * 256;
        if (q < 1400) {
            int e0 = q * 4;
            int l0 = e0 / 25;                   // one div per float4 (magic-mul)
            int s0 = e0 - l0 * 25;
#pragma unroll
            for (int c = 0; c < 4; ++c) {
                int s = s0 + c;
                int l = l0;
                if (s >= 25) { s -= 25; ++l; }  // carry (predicated)
                int idx = (((s >> 4) * NKC + (l >> 5)) * 64 +
                           ((s & 15) | (((l >> 3) & 3) << 4))) * 8 + (l & 7);
                float fv = c == 0 ? xf[k].x : c == 1 ? xf[k].y : c == 2 ? xf[k].z : xf[k].w;
                alds[idx] = f2bf(fv);
            }
        }
    }
    __syncthreads();

    // ---- phase 2: GEMM ----------------------------------------------------
    ffrag_t acck[2][NMT], accv[2][NMT], accq[2];
#pragma unroll
    for (int ti = 0; ti < 2; ++ti)
#pragma unroll
        for (int mt = 0; mt < NMT; ++mt) {
            acck[ti][mt] = ffrag_t{0.f, 0.f, 0.f, 0.f};
            accv[ti][mt] = ffrag_t{0.f, 0.f, 0.f, 0.f};
        }
    accq[0] = ffrag_t{0.f, 0.f, 0.f, 0.f};
    accq[1] = ffrag_t{0.f, 0.f, 0.f, 0.f};

#pragma unroll
    for (int kc = 0; kc < NKC; ++kc) {
        bfrag_t bk0 = *(const bfrag_t*)(wpack + ((kc * NNT + wave)      * 64 + lane) * 8);
        bfrag_t bk1 = *(const bfrag_t*)(wpack + ((kc * NNT + wave + 4)  * 64 + lane) * 8);
        bfrag_t bv0 = *(const bfrag_t*)(wpack + ((kc * NNT + wave + 8)  * 64 + lane) * 8);
        bfrag_t bv1 = *(const bfrag_t*)(wpack + ((kc * NNT + wave + 12) * 64 + lane) * 8);
        bfrag_t bq0 = *(const bfrag_t*)(wpack + ((kc * NNT + wave + 16) * 64 + lane) * 8);
        bfrag_t bq1 = *(const bfrag_t*)(wpack + ((kc * NNT + wave + 20) * 64 + lane) * 8);
        bfrag_t af0 = *(const bfrag_t*)(alds + ((0 * NKC + kc) * 64 + lane) * 8);
        bfrag_t af1 = *(const bfrag_t*)(alds + ((1 * NKC + kc) * 64 + lane) * 8);
        acck[0][0] = __builtin_amdgcn_mfma_f32_16x16x32_bf16(af0, bk0, acck[0][0], 0, 0, 0);
        acck[0][1] = __builtin_amdgcn_mfma_f32_16x16x32_bf16(af1, bk0, acck[0][1], 0, 0, 0);
        acck[1][0] = __builtin_amdgcn_mfma_f32_16x16x32_bf16(af0, bk1, acck[1][0], 0, 0, 0);
        acck[1][1] = __builtin_amdgcn_mfma_f32_16x16x32_bf16(af1, bk1, acck[1][1], 0, 0, 0);
        accv[0][0] = __builtin_amdgcn_mfma_f32_16x16x32_bf16(af0, bv0, accv[0][0], 0, 0, 0);
        accv[0][1] = __builtin_amdgcn_mfma_f32_16x16x32_bf16(af1, bv0, accv[0][1], 0, 0, 0);
        accv[1][0] = __builtin_amdgcn_mfma_f32_16x16x32_bf16(af0, bv1, accv[1][0], 0, 0, 0);
        accv[1][1] = __builtin_amdgcn_mfma_f32_16x16x32_bf16(af1, bv1, accv[1][1], 0, 0, 0);
        accq[0]    = __builtin_amdgcn_mfma_f32_16x16x32_bf16(af0, bq0, accq[0],    0, 0, 0);
        accq[1]    = __builtin_amdgcn_mfma_f32_16x16x32_bf16(af0, bq1, accq[1],    0, 0, 0);
    }
    __syncthreads();   // all A-frag reads done; alds becomes keys/vals

    // ---- phase 2b: C tiles -> LDS bf16; q -> qv ---------------------------
    // C/D layout: col = lane&15, row = (lane>>4)*4 + reg
    {
#pragma unroll
        for (int ti = 0; ti < 2; ++ti) {
            const int   col = ti ? c1 : c0;
            const float bk  = ti ? biask1 : biask0;
            const float bv  = ti ? biasv1 : biasv0;
#pragma unroll
            for (int mt = 0; mt < NMT; ++mt) {
#pragma unroll
                for (int reg = 0; reg < 4; ++reg) {
                    int s = mt * 16 + ((lane >> 4) << 2) + reg;
                    if (s < SS) {
                        alds[s * VST + col]         = f2bf(acck[ti][mt][reg] + bk);
                        alds[VBASE + s * VST + col] = f2bf(accv[ti][mt][reg] + bv);
                    }
                }
            }
        }
        if ((lane >> 4) == 3) {                 // reg0 -> row 12 (mt0)
            qv[c0] = accq[0][0] + biasq0;
            qv[c1] = accq[1][0] + biasq1;
        }
    }
    __syncthreads();

    // ---- phase 3: scores + shuffle softmax (4 rows x 64 lanes, full) ------
    {
        const int h    = wave;                  // head
        const int l32  = lane & 31;
        const int half = lane >> 5;
        float part = 0.f;
        if (l32 < SS) {
            const ushort* kr = alds + l32 * VST + h * 32 + half * 16;
            const float*  qr = qv + h * 32 + half * 16;
            float a0 = 0.f, a1 = 0.f, a2 = 0.f, a3 = 0.f;
#pragma unroll
            for (int i = 0; i < 16; i += 4) {
                a0 = fmaf(qr[i + 0], bfu2f(kr[i + 0]), a0);
                a1 = fmaf(qr[i + 1], bfu2f(kr[i + 1]), a1);
                a2 = fmaf(qr[i + 2], bfu2f(kr[i + 2]), a2);
                a3 = fmaf(qr[i + 3], bfu2f(kr[i + 3]), a3);
            }
            part = (a0 + a1) + (a2 + a3);
        }
        part += __shfl_xor(part, 32);           // combine the two 16-halves
        float sc = -1e30f;
        if (l32 < SS) {
            sc = part * 0.088388347648318447f;
            if (l32 == CTR) sc -= 1e6f;
        }
        float mx = sc;
#pragma unroll
        for (int m = 16; m > 0; m >>= 1) mx = fmaxf(mx, __shfl_xor(mx, m, 32));
        float e = __expf(sc - mx);
        float sum = e;
#pragma unroll
        for (int m = 16; m > 0; m >>= 1) sum += __shfl_xor(sum, m, 32);
        if (half == 0 && l32 < SS) att[h * 26 + l32] = e / sum;
    }
    __syncthreads();

    // ---- phase 4: surround / central / nearby gate / swish ----------------
    float sur = 0.f, cen = 0.f;
    if (t < 128) {
        const int d = t;
        const int h = d >> 5;
        const ushort* vrow = alds + VBASE + d;
        const float* arow = att + h * 26;
        float s0 = 0.f, s1 = 0.f;
#pragma unroll
        for (int s = 0; s < 24; s += 2) {
            s0 = fmaf(arow[s],     bfu2f(vrow[s * VST]),       s0);
            s1 = fmaf(arow[s + 1], bfu2f(vrow[(s + 1) * VST]), s1);
        }
        sur = fmaf(arow[24], bfu2f(vrow[24 * VST]), s0 + s1);
        cen = bfu2f(vrow[CTR * VST]);
        float term = (cen - sur) * ngw;
#pragma unroll
        for (int off = 32; off > 0; off >>= 1) term += __shfl_down(term, off);
        if (lane == 0) red[wave] = term;
    }
    __syncthreads();
    if (t < 128) {
        float tot = red[0] + red[1] + ng_b[0];
        float nearby = f_sigmoid(tot);
        float ssv = cen + nearby * sur;
        float sw  = ssv * f_sigmoid(ssv);
        swv_ws[(size_t)blockIdx.x * DD + t] = f2bf(sw);
    }
}

// ---- kC: FC1 + GLU as batched MFMA GEMM (M=8192, K=128, N=256) -------------
// 256 blocks x 32 rows; fused BN partial-sum accumulation via atomics.
// stats layout: [h_sum(64) | h_sq(64) | g_sum(64) | g_sq(64)]
__global__ __launch_bounds__(256) void kC_fc1(
    const ushort* __restrict__ swv_ws,
    const ushort* __restrict__ fc1pack,
    const float* __restrict__ f1_fb, const float* __restrict__ f1_gb,
    const float* __restrict__ s1_fb, const float* __restrict__ s1_gb,
    float* __restrict__ h1_ws, float* __restrict__ g1_ws,
    float* __restrict__ stats)
{
    const int t    = threadIdx.x;
    const int wave = t >> 6;
    const int lane = t & 63;
    const int m0   = blockIdx.x * 32;
    const int c16  = wave * 16 + (lane & 15);

    const float fb1 = f1_fb[c16], gb1 = f1_gb[c16];
    const float fb2 = s1_fb[c16], gb2 = s1_gb[c16];

    ffrag_t acc[4][2];
#pragma unroll
    for (int ni = 0; ni < 4; ++ni)
#pragma unroll
        for (int mt = 0; mt < 2; ++mt) acc[ni][mt] = ffrag_t{0.f, 0.f, 0.f, 0.f};

#pragma unroll
    for (int kc = 0; kc < 4; ++kc) {
        bfrag_t bf[4];
#pragma unroll
        for (int ni = 0; ni < 4; ++ni) {
            int nt = wave + 4 * ni;
            bf[ni] = *(const bfrag_t*)(fc1pack + ((kc * 16 + nt) * 64 + lane) * 8);
        }
#pragma unroll
        for (int mt = 0; mt < 2; ++mt) {
            bfrag_t af = *(const bfrag_t*)(swv_ws +
                (size_t)(m0 + mt * 16 + (lane & 15)) * DD + kc * 32 + ((lane >> 4) << 3));
#pragma unroll
            for (int ni = 0; ni < 4; ++ni)
                acc[ni][mt] = __builtin_amdgcn_mfma_f32_16x16x32_bf16(af, bf[ni], acc[ni][mt], 0, 0, 0);
        }
    }

    float hs = 0.f, hq = 0.f, gs = 0.f, gq = 0.f;
#pragma unroll
    for (int mt = 0; mt < 2; ++mt) {
#pragma unroll
        for (int reg = 0; reg < 4; ++reg) {
            int m = m0 + mt * 16 + ((lane >> 4) << 2) + reg;
            float hv = (acc[0][mt][reg] + fb1) * f_sigmoid(acc[1][mt][reg] + gb1);
            float gv = (acc[2][mt][reg] + fb2) * f_sigmoid(acc[3][mt][reg] + gb2);
            h1_ws[(size_t)m * HID + c16] = hv;
            g1_ws[(size_t)m * HID + c16] = gv;
            hs += hv; hq = fmaf(hv, hv, hq);
            gs += gv; gq = fmaf(gv, gv, gq);
        }
    }
    // reduce across the 4 row-groups (lanes sharing c16): xor 16, 32
    hs += __shfl_xor(hs, 16); hs += __shfl_xor(hs, 32);
    hq += __shfl_xor(hq, 16); hq += __shfl_xor(hq, 32);
    gs += __shfl_xor(gs, 16); gs += __shfl_xor(gs, 32);
    gq += __shfl_xor(gq, 16); gq += __shfl_xor(gq, 32);
    const int cg = lane >> 4;                   // 0:hs 1:hq 2:gs 3:gq
    float val = cg == 0 ? hs : cg == 1 ? hq : cg == 2 ? gs : gq;
    atomicAdd(&stats[cg * 64 + c16], val);
}

// ---- k3: tail, 16 batches per block; BN finalize inlined -------------------
#define K3G 16
__global__ __launch_bounds__(256) void k3_back(
    const float* __restrict__ h1, const float* __restrict__ g1,
    const float* __restrict__ stats,
    const float* __restrict__ f_bng, const float* __restrict__ f_bnb,
    const float* __restrict__ s_bng, const float* __restrict__ s_bnb,
    const float* __restrict__ f2_fw, const float* __restrict__ f2_fb,
    const float* __restrict__ f2_gw, const float* __restrict__ f2_gb,
    const float* __restrict__ s2_fw, const float* __restrict__ s2_fb,
    const float* __restrict__ s2_gw, const float* __restrict__ s2_gb,
    const float* __restrict__ endm,
    float* __restrict__ out_recon, float* __restrict__ out_abd,
    float* __restrict__ out_es)
{
    const int B0 = blockIdx.x * K3G;
    const int t = threadIdx.x;
    __shared__ float bnl[256];
    __shared__ float w2[4][HID * PP];   // f2_fw f2_gw s2_fw s2_gw
    __shared__ float b2[4][8];
    __shared__ float endl[PP * LL];
    __shared__ float hh[K3G * 65], gg[K3G * 65];
    __shared__ float logit[K3G * 8], esv[K3G * 8], coef[K3G * 8];

    if (t < 128) {                      // BN finalize (redundant per block, cheap)
        int br = t >> 6, j = t & 63;
        float S1 = stats[br * 128 + j];
        float S2 = stats[br * 128 + 64 + j];
        float m   = S1 * (1.0f / NB);
        float var = S2 * (1.0f / NB) - m * m;
        float gam = br ? s_bng[j] : f_bng[j];
        float be  = br ? s_bnb[j] : f_bnb[j];
        float a   = gam * rsqrtf(var + 1e-5f);
        bnl[br * 128 + j]      = a;
        bnl[br * 128 + 64 + j] = be - m * a;
    }
    for (int i = t; i < HID * PP; i += 256) {
        w2[0][i] = f2_fw[i];
        w2[1][i] = f2_gw[i];
        w2[2][i] = s2_fw[i];
        w2[3][i] = s2_gw[i];
    }
    if (t < PP) {
        b2[0][t] = f2_fb[t];
        b2[1][t] = f2_gb[t];
        b2[2][t] = s2_fb[t];
        b2[3][t] = s2_gb[t];
    }
    for (int i = t; i < PP * LL; i += 256) endl[i] = endm[i];
    __syncthreads();

    for (int i = t; i < K3G * HID; i += 256) {
        int ba = i >> 6, j = i & 63;
        float v1 = h1[(size_t)(B0 + ba) * HID + j] * bnl[j] + bnl[64 + j];
        hh[ba * 65 + j] = v1 * f_sigmoid(v1);
        float v2 = g1[(size_t)(B0 + ba) * HID + j] * bnl[128 + j] + bnl[192 + j];
        gg[ba * 65 + j] = v2 * f_sigmoid(v2);
    }
    __syncthreads();

    for (int i = t; i < K3G * 2 * PP; i += 256) {
        int ba = i / (2 * PP);
        int rr = i - ba * (2 * PP);
        int br = rr / PP;
        int p  = rr - br * PP;
        const float* src = (br ? gg : hh) + ba * 65;
        const float* fw  = w2[br * 2];
        const float* gw  = w2[br * 2 + 1];
        float df = b2[br * 2][p], dg = b2[br * 2 + 1][p];
#pragma unroll 8
        for (int j = 0; j < HID; ++j) {
            float v = src[j];
            df = fmaf(v, fw[j * PP + p], df);
            dg = fmaf(v, gw[j * PP + p], dg);
        }
        float glu = df * f_sigmoid(dg);
        if (br == 0) {
            logit[ba * 8 + p] = glu;
        } else {
            float e = tanhf(glu);
            esv[ba * 8 + p] = e;
            out_es[(size_t)(B0 + ba) * PP + p] = e;
        }
    }
    __syncthreads();

    if (t < K3G) {
        float mx = -1e30f;
#pragma unroll
        for (int p = 0; p < PP; ++p) mx = fmaxf(mx, logit[t * 8 + p]);
        float e[PP]; float sum = 0.f;
#pragma unroll
        for (int p = 0; p < PP; ++p) { e[p] = __expf(logit[t * 8 + p] - mx); sum += e[p]; }
        float inv = 1.0f / sum;
#pragma unroll
        for (int p = 0; p < PP; ++p) {
            float a = e[p] * inv;
            out_abd[(size_t)(B0 + t) * PP + p] = a;
            coef[t * 8 + p] = a * (1.0f + 0.2f * esv[t * 8 + p]);
        }
    }
    __syncthreads();

    for (int i = t; i < K3G * LL; i += 256) {
        int ba = i / LL;
        int l  = i - ba * LL;
        float r = 0.f;
#pragma unroll
        for (int p = 0; p < PP; ++p)
            r = fmaf(coef[ba * 8 + p], endl[p * LL + l], r);
        out_recon[(size_t)(B0 + ba) * LL + l] = r;
    }
}

extern "C" void kernel_launch(void* const* d_in, const int* in_sizes, int n_in,
                              void* d_out, int out_size, void* d_ws, size_t ws_size,
                              hipStream_t stream)
{
    const float* x     = (const float*)d_in[0];
    const float* wk_w  = (const float*)d_in[1];
    const float* wk_b  = (const float*)d_in[2];
    const float* wv_w  = (const float*)d_in[3];
    const float* wv_b  = (const float*)d_in[4];
    const float* wq_w  = (const float*)d_in[5];
    const float* wq_b  = (const float*)d_in[6];
    const float* ng_w  = (const float*)d_in[7];
    const float* ng_b  = (const float*)d_in[8];
    const float* f1_fw = (const float*)d_in[9];
    const float* f1_fb = (const float*)d_in[10];
    const float* f1_gw = (const float*)d_in[11];
    const float* f1_gb = (const float*)d_in[12];
    const float* f_bng = (const float*)d_in[13];
    const float* f_bnb = (const float*)d_in[14];
    const float* f2_fw = (const float*)d_in[15];
    const float* f2_fb = (const float*)d_in[16];
    const float* f2_gw = (const float*)d_in[17];
    const float* f2_gb = (const float*)d_in[18];
    const float* s1_fw = (const float*)d_in[19];
    const float* s1_fb = (const float*)d_in[20];
    const float* s1_gw = (const float*)d_in[21];
    const float* s1_gb = (const float*)d_in[22];
    const float* s_bng = (const float*)d_in[23];
    const float* s_bnb = (const float*)d_in[24];
    const float* s2_fw = (const float*)d_in[25];
    const float* s2_fb = (const float*)d_in[26];
    const float* s2_gw = (const float*)d_in[27];
    const float* s2_gb = (const float*)d_in[28];
    const float* endm  = (const float*)d_in[29];

    float* ws = (float*)d_ws;
    float*  h1_ws   = ws;                                   // NB*64
    float*  g1_ws   = ws + (size_t)NB * HID;                // NB*64
    float*  stats   = ws + 1048576;                         // 256
    ushort* wpack   = (ushort*)(ws + 1048832);              // 86016 ushort
    ushort* fc1pack = (ushort*)(ws + 1048832 + WPK_ELEMS / 2);          // 32768 ushort
    ushort* swv_ws  = (ushort*)(ws + 1048832 + (WPK_ELEMS + FC1_ELEMS) / 2); // NB*128

    float* out       = (float*)d_out;
    float* out_recon = out;                              // NB*LL
    float* out_abd   = out + (size_t)NB * LL;            // NB*PP
    float* out_es    = out + (size_t)NB * (LL + PP);     // NB*PP

    k0_pack<<<NNT + 16, 256, 0, stream>>>(wk_w, wv_w, wq_w, f1_fw, f1_gw,
                                          s1_fw, s1_gw, wpack, fc1pack, stats);
    kA_front<<<NB, 256, 0, stream>>>(x, wpack, wk_b, wv_b, wq_b,
                                     ng_w, ng_b, swv_ws);
    kC_fc1<<<NB / 32, 256, 0, stream>>>(swv_ws, fc1pack, f1_fb, f1_gb,
                                        s1_fb, s1_gb, h1_ws, g1_ws, stats);
    k3_back<<<NB / K3G, 256, 0, stream>>>(h1_ws, g1_ws, stats,
                                          f_bng, f_bnb, s_bng, s_bnb,
                                          f2_fw, f2_fb, f2_gw, f2_gb,
                                          s2_fw, s2_fb, s2_gw, s2_gb,
                                          endm, out_recon, out_abd, out_es);
}

// Round 7
// 358.644 us; speedup vs baseline: 1.0769x; 1.0769x over previous
//
#include <hip/hip_runtime.h>
#include <hip/hip_bf16.h>

typedef unsigned short ushort;
typedef unsigned int   uint;
typedef __bf16 bfrag_t __attribute__((ext_vector_type(8)));   // 8 bf16 = 4 VGPRs
typedef float  ffrag_t __attribute__((ext_vector_type(4)));   // 4 f32 acc

#define NB   8192   // batch
#define LL   224    // spectral bands
#define SS   25     // K*K
#define CTR  12     // center index
#define DD   128    // model dim
#define PP   6      // endmembers
#define HID  64     // hidden
#define GPB  2      // batches per group
#define NGRP 4      // groups per kA block (R7: prefetch issued in low-pressure zone)
#define NKC  7      // K-chunks of 32 (224/32)
#define NMT  4      // M-tiles of 16 (2 batches * 32 rows)
#define NNT  24     // n-tiles of 16 (384 cols = wk|wv|wq)
#define VST  132    // ushort LDS row stride for keys/vals
#define VBASE (GPB * SS * VST)                 // 6600: vals base in alds
#define WPK_ELEMS (NKC * NNT * 64 * 8)         // 86016
#define FC1_ELEMS (4 * 16 * 64 * 8)            // 32768

__device__ __forceinline__ float f_sigmoid(float x) { return 1.0f / (1.0f + __expf(-x)); }
__device__ __forceinline__ ushort f2bf(float f) {
    __hip_bfloat16 h = __float2bfloat16(f);
    ushort u; __builtin_memcpy(&u, &h, 2); return u;
}
__device__ __forceinline__ float bfu2f(ushort u) {
    uint v = ((uint)u) << 16; float f; __builtin_memcpy(&f, &v, 4); return f;
}

// ---- k0: pack [wk|wv|wq] (24 tiles) + [f1f|f1g|s1f|s1g] (16 tiles); zero stats
// B-frag: lane holds B[k = kc*32+(lane>>4)*8+j][n = nt*16+(lane&15)]
__global__ __launch_bounds__(256) void k0_pack(
    const float* __restrict__ wk_w, const float* __restrict__ wv_w,
    const float* __restrict__ wq_w,
    const float* __restrict__ f1_fw, const float* __restrict__ f1_gw,
    const float* __restrict__ s1_fw, const float* __restrict__ s1_gw,
    ushort* __restrict__ wpack, ushort* __restrict__ fc1pack,
    float* __restrict__ stats)
{
    const int blk = blockIdx.x;
    if (blk == 0) stats[threadIdx.x] = 0.f;     // 256 entries, zero for kC atomics
    if (blk < NNT) {                            // wkvq: K=224, ld=128
        const int nt  = blk;
        const int mat = nt >> 3;
        const float* w = mat == 0 ? wk_w : (mat == 1 ? wv_w : wq_w);
        const int cb = (nt & 7) * 16;
        for (int e = threadIdx.x; e < NKC * 64 * 8; e += 256) {
            int j    = e & 7;
            int lane = (e >> 3) & 63;
            int kc   = e >> 9;
            int k = kc * 32 + ((lane >> 4) << 3) + j;
            int c = cb + (lane & 15);
            wpack[((kc * NNT + nt) * 64 + lane) * 8 + j] = f2bf(w[k * DD + c]);
        }
    } else {                                    // fc1: K=128, ld=64, 4 mats
        const int nt = blk - NNT;               // 0..15
        const int m2 = nt >> 2;                 // 0:f1f 1:f1g 2:s1f 3:s1g
        const float* w = m2 == 0 ? f1_fw : (m2 == 1 ? f1_gw : (m2 == 2 ? s1_fw : s1_gw));
        const int cb = (nt & 3) * 16;
        for (int e = threadIdx.x; e < 4 * 64 * 8; e += 256) {
            int j    = e & 7;
            int lane = (e >> 3) & 63;
            int kc   = e >> 9;
            int k = kc * 32 + ((lane >> 4) << 3) + j;
            int c = cb + (lane & 15);
            fc1pack[((kc * 16 + nt) * 64 + lane) * 8 + j] = f2bf(w[k * HID + c]);
        }
    }
}

// ---- kA: MFMA K/V/Q GEMM + attention + nearby gate + swish -----------------
// 512 threads = 8 waves. Wave w: kv-nt {w (keys), w+8 (vals)}, q-nt {16+w}.
// R7: NGRP=4 groups/block; x prefetch for j+1 issued AFTER phase 2b (acc
// frags dead -> no spill; R4's failure was VGPR cap 64 + early placement).
// __launch_bounds__(512,2): VGPR cap 128.
__global__ __launch_bounds__(512, 2) void kA_front(
    const float* __restrict__ x,
    const ushort* __restrict__ wpack,
    const float* __restrict__ wk_b, const float* __restrict__ wv_b,
    const float* __restrict__ wq_b,
    const float* __restrict__ ng_w, const float* __restrict__ ng_b,
    ushort* __restrict__ swv_ws)
{
    // A fragments: 4 mt * 7 kc * 64 lanes * 8 = 14336 ushort (28672 B)
    // after GEMM reused: keys[0:6600) vals[6600:13200) as [g][s][VST] ushort
    __shared__ ushort alds[NMT * NKC * 64 * 8];
    __shared__ float  qv[GPB * DD];
    __shared__ float  att[8 * 26];
    __shared__ float  red[4];

    const int t    = threadIdx.x;
    const int wave = t >> 6;
    const int lane = t & 63;

    // hoisted small loads (amortized over NGRP groups)
    const int cC = wave * 16 + (lane & 15);
    const float biask = wk_b[cC];
    const float biasv = wv_b[cC];
    const float biasq = wq_b[cC];
    const float ngw   = ng_w[t & 127];

    // ---- prologue: x prefetch for group 0 (2800 float4 per group) ---------
    float4 xf[6];
    {
        const float4* xb4 = (const float4*)(x + (size_t)(blockIdx.x * NGRP) * GPB * (LL * SS));
#pragma unroll
        for (int k = 0; k < 6; ++k) {
            int q = t + k * 512;
            if (q < 2800) xf[k] = xb4[q];
        }
    }

    for (int j = 0; j < NGRP; ++j) {
        const int b0 = (blockIdx.x * NGRP + j) * GPB;

        // ---- phase 1: scatter prefetched x into alds (bf16 A-frags) -------
#pragma unroll
        for (int k = 0; k < 6; ++k) {
            int q = t + k * 512;
            if (q < 2800) {
                int e0 = q * 4;
                int g  = e0 >= 5600;
                int eb0 = e0 - g * 5600;        // float4 never crosses batch (5600%4==0)
                int l0 = eb0 / 25;              // one div per float4 (magic-mul)
                int s0 = eb0 - l0 * 25;
#pragma unroll
                for (int c = 0; c < 4; ++c) {
                    int s = s0 + c;
                    int l = l0;
                    if (s >= 25) { s -= 25; ++l; }  // carry (predicated)
                    int r = g * 32 + s;
                    int idx = (((r >> 4) * NKC + (l >> 5)) * 64 +
                               ((r & 15) | (((l >> 3) & 3) << 4))) * 8 + (l & 7);
                    float fv = c == 0 ? xf[k].x : c == 1 ? xf[k].y : c == 2 ? xf[k].z : xf[k].w;
                    alds[idx] = f2bf(fv);
                }
            }
        }
        __syncthreads();

        // ---- phase 2: GEMM, B-frags software-pipelined --------------------
        ffrag_t acck[NMT], accv[NMT], accq[2];
#pragma unroll
        for (int mt = 0; mt < NMT; ++mt) {
            acck[mt] = ffrag_t{0.f, 0.f, 0.f, 0.f};
            accv[mt] = ffrag_t{0.f, 0.f, 0.f, 0.f};
        }
        accq[0] = ffrag_t{0.f, 0.f, 0.f, 0.f};
        accq[1] = ffrag_t{0.f, 0.f, 0.f, 0.f};

        bfrag_t bk = *(const bfrag_t*)(wpack + ((0 * NNT + wave) * 64 + lane) * 8);
        bfrag_t bv = *(const bfrag_t*)(wpack + ((0 * NNT + wave + 8) * 64 + lane) * 8);
        bfrag_t bq = *(const bfrag_t*)(wpack + ((0 * NNT + wave + 16) * 64 + lane) * 8);
#pragma unroll
        for (int kc = 0; kc < NKC; ++kc) {
            bfrag_t nbk, nbv, nbq;
            if (kc + 1 < NKC) {
                nbk = *(const bfrag_t*)(wpack + (((kc + 1) * NNT + wave) * 64 + lane) * 8);
                nbv = *(const bfrag_t*)(wpack + (((kc + 1) * NNT + wave + 8) * 64 + lane) * 8);
                nbq = *(const bfrag_t*)(wpack + (((kc + 1) * NNT + wave + 16) * 64 + lane) * 8);
            }
#pragma unroll
            for (int mt = 0; mt < NMT; ++mt) {
                bfrag_t af = *(const bfrag_t*)(alds + ((mt * NKC + kc) * 64 + lane) * 8);
                acck[mt] = __builtin_amdgcn_mfma_f32_16x16x32_bf16(af, bk, acck[mt], 0, 0, 0);
                accv[mt] = __builtin_amdgcn_mfma_f32_16x16x32_bf16(af, bv, accv[mt], 0, 0, 0);
                if ((mt & 1) == 0)
                    accq[mt >> 1] = __builtin_amdgcn_mfma_f32_16x16x32_bf16(af, bq, accq[mt >> 1], 0, 0, 0);
            }
            if (kc + 1 < NKC) { bk = nbk; bv = nbv; bq = nbq; }
        }
        __syncthreads();   // all A-frag reads done; alds becomes keys/vals

        // ---- phase 2b: C tiles -> LDS bf16; q -> qv -----------------------
        // C/D layout: col = lane&15, row = (lane>>4)*4 + reg
        {
#pragma unroll
            for (int mt = 0; mt < NMT; ++mt) {
#pragma unroll
                for (int reg = 0; reg < 4; ++reg) {
                    int r = mt * 16 + ((lane >> 4) << 2) + reg;
                    int g = r >> 5;
                    int s = r & 31;
                    if (s < SS) {
                        alds[(g * SS + s) * VST + cC]         = f2bf(acck[mt][reg] + biask);
                        alds[VBASE + (g * SS + s) * VST + cC] = f2bf(accv[mt][reg] + biasv);
                    }
                }
            }
            if ((lane >> 4) == 3) {             // reg0 -> rows 12 (mt0) / 44 (mt2)
                qv[cC]      = accq[0][0] + biasq;
                qv[DD + cC] = accq[1][0] + biasq;
            }
        }
        __syncthreads();

        // ---- prefetch x for group j+1 (acc frags dead: low VGPR pressure;
        //      HBM/L3 latency hides under phases 3-4 + next barriers) -------
        if (j + 1 < NGRP) {
            const float4* xb4 = (const float4*)(x + (size_t)(b0 + GPB) * (LL * SS));
#pragma unroll
            for (int k = 0; k < 6; ++k) {
                int q = t + k * 512;
                if (q < 2800) xf[k] = xb4[q];
            }
        }

        // ---- phase 3: scores + shuffle softmax (8 rows x 64 lanes) --------
        {
            const int r    = t >> 6;            // g*4+h = wave index
            const int g    = r >> 2;
            const int h    = r & 3;
            const int l32  = lane & 31;
            const int half = lane >> 5;
            float part = 0.f;
            if (l32 < SS) {
                const ushort* kr = alds + (g * SS + l32) * VST + h * 32 + half * 16;
                const float*  qr = qv + g * DD + h * 32 + half * 16;
                float a0 = 0.f, a1 = 0.f, a2 = 0.f, a3 = 0.f;
#pragma unroll
                for (int i = 0; i < 16; i += 4) {
                    a0 = fmaf(qr[i + 0], bfu2f(kr[i + 0]), a0);
                    a1 = fmaf(qr[i + 1], bfu2f(kr[i + 1]), a1);
                    a2 = fmaf(qr[i + 2], bfu2f(kr[i + 2]), a2);
                    a3 = fmaf(qr[i + 3], bfu2f(kr[i + 3]), a3);
                }
                part = (a0 + a1) + (a2 + a3);
            }
            part += __shfl_xor(part, 32);       // combine the two 16-halves
            float sc = -1e30f;
            if (l32 < SS) {
                sc = part * 0.088388347648318447f;
                if (l32 == CTR) sc -= 1e6f;
            }
            float mx = sc;
#pragma unroll
            for (int m = 16; m > 0; m >>= 1) mx = fmaxf(mx, __shfl_xor(mx, m, 32));
            float e = __expf(sc - mx);
            float sum = e;
#pragma unroll
            for (int m = 16; m > 0; m >>= 1) sum += __shfl_xor(sum, m, 32);
            if (half == 0 && l32 < SS) att[r * 26 + l32] = e / sum;
        }
        __syncthreads();

        // ---- phase 4: surround / central / nearby gate / swish ------------
        if (t < 256) {
            const int g = t >> 7;
            const int d = t & 127;
            const int h = d >> 5;
            const ushort* vrow = alds + VBASE + g * SS * VST + d;
            const float* arow = att + (g * 4 + h) * 26;
            float s0 = 0.f, s1 = 0.f;
#pragma unroll
            for (int s = 0; s < 24; s += 2) {
                s0 = fmaf(arow[s],     bfu2f(vrow[s * VST]),       s0);
                s1 = fmaf(arow[s + 1], bfu2f(vrow[(s + 1) * VST]), s1);
            }
            float sur = fmaf(arow[24], bfu2f(vrow[24 * VST]), s0 + s1);
            float cen = bfu2f(vrow[CTR * VST]);
            float term = (cen - sur) * ngw;
#pragma unroll
            for (int off = 32; off > 0; off >>= 1) term += __shfl_down(term, off);
            if (lane == 0) red[wave] = term;
            __syncthreads();                    // all alds/att reads complete
            float tot = red[g * 2] + red[g * 2 + 1] + ng_b[0];
            float nearby = f_sigmoid(tot);
            float ssv = cen + nearby * sur;
            float sw  = ssv * f_sigmoid(ssv);
            swv_ws[(size_t)(b0 + g) * DD + d] = f2bf(sw);
        } else {
            __syncthreads();
        }
        // next iteration's scatter touches alds only after the barrier above;
        // all reads of alds/att/qv for this group completed before it.
    }
}

// ---- kC: FC1 + GLU as batched MFMA GEMM (M=8192, K=128, N=256) -------------
// 256 blocks x 32 rows; fused BN partial-sum accumulation via atomics.
// stats layout: [h_sum(64) | h_sq(64) | g_sum(64) | g_sq(64)]
__global__ __launch_bounds__(256) void kC_fc1(
    const ushort* __restrict__ swv_ws,
    const ushort* __restrict__ fc1pack,
    const float* __restrict__ f1_fb, const float* __restrict__ f1_gb,
    const float* __restrict__ s1_fb, const float* __restrict__ s1_gb,
    float* __restrict__ h1_ws, float* __restrict__ g1_ws,
    float* __restrict__ stats)
{
    const int t    = threadIdx.x;
    const int wave = t >> 6;
    const int lane = t & 63;
    const int m0   = blockIdx.x * 32;
    const int c16  = wave * 16 + (lane & 15);

    const float fb1 = f1_fb[c16], gb1 = f1_gb[c16];
    const float fb2 = s1_fb[c16], gb2 = s1_gb[c16];

    ffrag_t acc[4][2];
#pragma unroll
    for (int ni = 0; ni < 4; ++ni)
#pragma unroll
        for (int mt = 0; mt < 2; ++mt) acc[ni][mt] = ffrag_t{0.f, 0.f, 0.f, 0.f};

#pragma unroll
    for (int kc = 0; kc < 4; ++kc) {
        bfrag_t bf[4];
#pragma unroll
        for (int ni = 0; ni < 4; ++ni) {
            int nt = wave + 4 * ni;
            bf[ni] = *(const bfrag_t*)(fc1pack + ((kc * 16 + nt) * 64 + lane) * 8);
        }
#pragma unroll
        for (int mt = 0; mt < 2; ++mt) {
            bfrag_t af = *(const bfrag_t*)(swv_ws +
                (size_t)(m0 + mt * 16 + (lane & 15)) * DD + kc * 32 + ((lane >> 4) << 3));
#pragma unroll
            for (int ni = 0; ni < 4; ++ni)
                acc[ni][mt] = __builtin_amdgcn_mfma_f32_16x16x32_bf16(af, bf[ni], acc[ni][mt], 0, 0, 0);
        }
    }

    float hs = 0.f, hq = 0.f, gs = 0.f, gq = 0.f;
#pragma unroll
    for (int mt = 0; mt < 2; ++mt) {
#pragma unroll
        for (int reg = 0; reg < 4; ++reg) {
            int m = m0 + mt * 16 + ((lane >> 4) << 2) + reg;
            float hv = (acc[0][mt][reg] + fb1) * f_sigmoid(acc[1][mt][reg] + gb1);
            float gv = (acc[2][mt][reg] + fb2) * f_sigmoid(acc[3][mt][reg] + gb2);
            h1_ws[(size_t)m * HID + c16] = hv;
            g1_ws[(size_t)m * HID + c16] = gv;
            hs += hv; hq = fmaf(hv, hv, hq);
            gs += gv; gq = fmaf(gv, gv, gq);
        }
    }
    // reduce across the 4 row-groups (lanes sharing c16): xor 16, 32
    hs += __shfl_xor(hs, 16); hs += __shfl_xor(hs, 32);
    hq += __shfl_xor(hq, 16); hq += __shfl_xor(hq, 32);
    gs += __shfl_xor(gs, 16); gs += __shfl_xor(gs, 32);
    gq += __shfl_xor(gq, 16); gq += __shfl_xor(gq, 32);
    const int cg = lane >> 4;                   // 0:hs 1:hq 2:gs 3:gq
    float val = cg == 0 ? hs : cg == 1 ? hq : cg == 2 ? gs : gq;
    atomicAdd(&stats[cg * 64 + c16], val);
}

// ---- k3: tail, 16 batches per block; BN finalize inlined -------------------
#define K3G 16
__global__ __launch_bounds__(256) void k3_back(
    const float* __restrict__ h1, const float* __restrict__ g1,
    const float* __restrict__ stats,
    const float* __restrict__ f_bng, const float* __restrict__ f_bnb,
    const float* __restrict__ s_bng, const float* __restrict__ s_bnb,
    const float* __restrict__ f2_fw, const float* __restrict__ f2_fb,
    const float* __restrict__ f2_gw, const float* __restrict__ f2_gb,
    const float* __restrict__ s2_fw, const float* __restrict__ s2_fb,
    const float* __restrict__ s2_gw, const float* __restrict__ s2_gb,
    const float* __restrict__ endm,
    float* __restrict__ out_recon, float* __restrict__ out_abd,
    float* __restrict__ out_es)
{
    const int B0 = blockIdx.x * K3G;
    const int t = threadIdx.x;
    __shared__ float bnl[256];
    __shared__ float w2[4][HID * PP];   // f2_fw f2_gw s2_fw s2_gw
    __shared__ float b2[4][8];
    __shared__ float endl[PP * LL];
    __shared__ float hh[K3G * 65], gg[K3G * 65];
    __shared__ float logit[K3G * 8], esv[K3G * 8], coef[K3G * 8];

    if (t < 128) {                      // BN finalize (redundant per block, cheap)
        int br = t >> 6, j = t & 63;
        float S1 = stats[br * 128 + j];
        float S2 = stats[br * 128 + 64 + j];
        float m   = S1 * (1.0f / NB);
        float var = S2 * (1.0f / NB) - m * m;
        float gam = br ? s_bng[j] : f_bng[j];
        float be  = br ? s_bnb[j] : f_bnb[j];
        float a   = gam * rsqrtf(var + 1e-5f);
        bnl[br * 128 + j]      = a;
        bnl[br * 128 + 64 + j] = be - m * a;
    }
    for (int i = t; i < HID * PP; i += 256) {
        w2[0][i] = f2_fw[i];
        w2[1][i] = f2_gw[i];
        w2[2][i] = s2_fw[i];
        w2[3][i] = s2_gw[i];
    }
    if (t < PP) {
        b2[0][t] = f2_fb[t];
        b2[1][t] = f2_gb[t];
        b2[2][t] = s2_fb[t];
        b2[3][t] = s2_gb[t];
    }
    for (int i = t; i < PP * LL; i += 256) endl[i] = endm[i];
    __syncthreads();

    for (int i = t; i < K3G * HID; i += 256) {
        int ba = i >> 6, j = i & 63;
        float v1 = h1[(size_t)(B0 + ba) * HID + j] * bnl[j] + bnl[64 + j];
        hh[ba * 65 + j] = v1 * f_sigmoid(v1);
        float v2 = g1[(size_t)(B0 + ba) * HID + j] * bnl[128 + j] + bnl[192 + j];
        gg[ba * 65 + j] = v2 * f_sigmoid(v2);
    }
    __syncthreads();

    for (int i = t; i < K3G * 2 * PP; i += 256) {
        int ba = i / (2 * PP);
        int rr = i - ba * (2 * PP);
        int br = rr / PP;
        int p  = rr - br * PP;
        const float* src = (br ? gg : hh) + ba * 65;
        const float* fw  = w2[br * 2];
        const float* gw  = w2[br * 2 + 1];
        float df = b2[br * 2][p], dg = b2[br * 2 + 1][p];
#pragma unroll 8
        for (int j = 0; j < HID; ++j) {
            float v = src[j];
            df = fmaf(v, fw[j * PP + p], df);
            dg = fmaf(v, gw[j * PP + p], dg);
        }
        float glu = df * f_sigmoid(dg);
        if (br == 0) {
            logit[ba * 8 + p] = glu;
        } else {
            float e = tanhf(glu);
            esv[ba * 8 + p] = e;
            out_es[(size_t)(B0 + ba) * PP + p] = e;
        }
    }
    __syncthreads();

    if (t < K3G) {
        float mx = -1e30f;
#pragma unroll
        for (int p = 0; p < PP; ++p) mx = fmaxf(mx, logit[t * 8 + p]);
        float e[PP]; float sum = 0.f;
#pragma unroll
        for (int p = 0; p < PP; ++p) { e[p] = __expf(logit[t * 8 + p] - mx); sum += e[p]; }
        float inv = 1.0f / sum;
#pragma unroll
        for (int p = 0; p < PP; ++p) {
            float a = e[p] * inv;
            out_abd[(size_t)(B0 + t) * PP + p] = a;
            coef[t * 8 + p] = a * (1.0f + 0.2f * esv[t * 8 + p]);
        }
    }
    __syncthreads();

    for (int i = t; i < K3G * LL; i += 256) {
        int ba = i / LL;
        int l  = i - ba * LL;
        float r = 0.f;
#pragma unroll
        for (int p = 0; p < PP; ++p)
            r = fmaf(coef[ba * 8 + p], endl[p * LL + l], r);
        out_recon[(size_t)(B0 + ba) * LL + l] = r;
    }
}

extern "C" void kernel_launch(void* const* d_in, const int* in_sizes, int n_in,
                              void* d_out, int out_size, void* d_ws, size_t ws_size,
                              hipStream_t stream)
{
    const float* x     = (const float*)d_in[0];
    const float* wk_w  = (const float*)d_in[1];
    const float* wk_b  = (const float*)d_in[2];
    const float* wv_w  = (const float*)d_in[3];
    const float* wv_b  = (const float*)d_in[4];
    const float* wq_w  = (const float*)d_in[5];
    const float* wq_b  = (const float*)d_in[6];
    const float* ng_w  = (const float*)d_in[7];
    const float* ng_b  = (const float*)d_in[8];
    const float* f1_fw = (const float*)d_in[9];
    const float* f1_fb = (const float*)d_in[10];
    const float* f1_gw = (const float*)d_in[11];
    const float* f1_gb = (const float*)d_in[12];
    const float* f_bng = (const float*)d_in[13];
    const float* f_bnb = (const float*)d_in[14];
    const float* f2_fw = (const float*)d_in[15];
    const float* f2_fb = (const float*)d_in[16];
    const float* f2_gw = (const float*)d_in[17];
    const float* f2_gb = (const float*)d_in[18];
    const float* s1_fw = (const float*)d_in[19];
    const float* s1_fb = (const float*)d_in[20];
    const float* s1_gw = (const float*)d_in[21];
    const float* s1_gb = (const float*)d_in[22];
    const float* s_bng = (const float*)d_in[23];
    const float* s_bnb = (const float*)d_in[24];
    const float* s2_fw = (const float*)d_in[25];
    const float* s2_fb = (const float*)d_in[26];
    const float* s2_gw = (const float*)d_in[27];
    const float* s2_gb = (const float*)d_in[28];
    const float* endm  = (const float*)d_in[29];

    float* ws = (float*)d_ws;
    float*  h1_ws   = ws;                                   // NB*64
    float*  g1_ws   = ws + (size_t)NB * HID;                // NB*64
    float*  stats   = ws + 1048576;                         // 256
    ushort* wpack   = (ushort*)(ws + 1048832);              // 86016 ushort
    ushort* fc1pack = (ushort*)(ws + 1048832 + WPK_ELEMS / 2);          // 32768 ushort
    ushort* swv_ws  = (ushort*)(ws + 1048832 + (WPK_ELEMS + FC1_ELEMS) / 2); // NB*128

    float* out       = (float*)d_out;
    float* out_recon = out;                              // NB*LL
    float* out_abd   = out + (size_t)NB * LL;            // NB*PP
    float* out_es    = out + (size_t)NB * (LL + PP);     // NB*PP

    k0_pack<<<NNT + 16, 256, 0, stream>>>(wk_w, wv_w, wq_w, f1_fw, f1_gw,
                                          s1_fw, s1_gw, wpack, fc1pack, stats);
    kA_front<<<NB / (GPB * NGRP), 512, 0, stream>>>(x, wpack, wk_b, wv_b, wq_b,
                                                    ng_w, ng_b, swv_ws);
    kC_fc1<<<NB / 32, 256, 0, stream>>>(swv_ws, fc1pack, f1_fb, f1_gb,
                                        s1_fb, s1_gb, h1_ws, g1_ws, stats);
    k3_back<<<NB / K3G, 256, 0, stream>>>(h1_ws, g1_ws, stats,
                                          f_bng, f_bnb, s_bng, s_bnb,
                                          f2_fw, f2_fb, f2_gw, f2_gb,
                                          s2_fw, s2_fb, s2_gw, s2_gb,
                                          endm, out_recon, out_abd, out_es);
}